// Round 10
// baseline (87.244 us; speedup 1.0000x reference)
//
#include <hip/hip_runtime.h>

#define Dq   256
#define ATTR 400
#define HW   3136
#define NB   32

typedef __attribute__((ext_vector_type(8))) short bf16x8;
typedef __attribute__((ext_vector_type(4))) float f32x4;

__device__ __forceinline__ unsigned short f2bf(float f) {
  unsigned int x = __float_as_uint(f);
  return (unsigned short)((x + 0x7FFFu + ((x >> 16) & 1u)) >> 16);
}

// ---------------- Kernel A: per-batch count-sketch vector sk1[b][256] ----------------
__global__ __launch_bounds__(256) void k_sk1(
    const float* __restrict__ oh, const float* __restrict__ W_emb,
    const float* __restrict__ b_emb, const float* __restrict__ conv_w,
    const float* __restrict__ conv_b, const int* __restrict__ h1,
    const float* __restrict__ s1, float* __restrict__ sk1_out) {
  __shared__ float ohs[ATTR];
  __shared__ float ts[Dq];
  __shared__ float sk[Dq];
  const int b = blockIdx.x, tid = threadIdx.x;
  for (int j = tid; j < ATTR; j += 256) ohs[j] = oh[b * ATTR + j];
  sk[tid] = 0.f;
  __syncthreads();
  float acc = b_emb[tid];
  const float* wr = W_emb + tid * ATTR;
  for (int j = 0; j < ATTR; ++j) acc = fmaf(ohs[j], wr[j], acc);
  ts[tid] = acc;
  __syncthreads();
  float a = conv_b[tid];
  const float* cr = conv_w + tid * Dq;
  for (int k = 0; k < Dq; ++k) a = fmaf(ts[k], cr[k], a);
  atomicAdd(&sk[h1[tid]], a * s1[tid]);
  __syncthreads();
  sk1_out[b * Dq + tid] = sk[tid];
}

// ---------------- Kernel B: circular conv + scatter straight into MFMA A-fragment layout ----------------
// Block (b,o). thread tid = c. Writes Abuf[b][frag][lane][j] (bf16) where
// A[m=o][k=c] = G[b][c][o] = s2[c] * T[o,h2[c]]:
//   frag = (o>>4)*8 + (c>>5), lane = (o&15) | (((c>>3)&3)<<4), j = c&7.
__global__ __launch_bounds__(256) void k_G(
    const float* __restrict__ sk1, const float* __restrict__ conv1_w,
    const int* __restrict__ h2, const float* __restrict__ s2,
    unsigned short* __restrict__ Abuf) {
  __shared__ float sks[Dq];
  __shared__ float w1[Dq];
  __shared__ float Tl[Dq];
  const int b = blockIdx.x >> 5, o = blockIdx.x & 31, c = threadIdx.x;
  sks[c] = sk1[b * Dq + c];
  w1[c]  = conv1_w[o * Dq + c];
  __syncthreads();
  float t = 0.f;
  for (int d = 0; d < Dq; ++d) t = fmaf(w1[d], sks[(d - c) & 255], t);
  Tl[c] = t;
  __syncthreads();
  const float g = s2[c] * Tl[h2[c]];
  const int frag = (o >> 4) * 8 + (c >> 5);
  const int lane = (o & 15) | (((c >> 3) & 3) << 4);
  Abuf[(((size_t)b * 16 + frag) * 64 + lane) * 8 + (c & 7)] = f2bf(g);
}

// ---------------- Fused kernel: load-once MFMA gate + sigmoid + store-once multiply ----------------
// Wave = 16 pixels x 256 channels; lane l owns pixel px0+(l&15), 64 channels
// ch(j) = (j>>3)*32 + (l>>4)*8 + (j&7). The 64 loads are VOLATILE: clang
// must issue them in program order with no sinking/remat -> all 64 in
// flight per lane, values held live in VGPRs for both the MFMA phase and
// the final feature store. Consumption follows load order so partial
// vmcnt waits pipeline naturally. No LDS, no barriers.
__global__ __launch_bounds__(256, 4) void k_fused(
    const float* __restrict__ ent,            // [B,256,HW]
    const unsigned short* __restrict__ Abuf,  // [B,16,64,8]
    const float* __restrict__ c1b, const float* __restrict__ c2w,
    const float* __restrict__ c2b,
    float* __restrict__ out)                  // map [B,HW] then feat [B,256,HW]
{
  const int b = blockIdx.y, tid = threadIdx.x;
  const int w = tid >> 6, l = tid & 63;
  const int px0 = blockIdx.x * 64 + w * 16;
  const int krow = (l >> 4) * 8;

  const volatile float* ep = ent + (size_t)b * Dq * HW + px0 + (l & 15);

  // ---- issue ALL 64 loads up-front, program-ordered ----
  float e[64];
#pragma unroll
  for (int j = 0; j < 64; ++j) {
    const int ch = (j >> 3) * 32 + krow + (j & 7);
    e[j] = ep[(size_t)ch * HW];
  }

  // ---- gate GEMM on MFMA; A-fragments loaded just-in-time (L2-hot) ----
  const unsigned short* Ab = Abuf + ((size_t)b * 16 * 64 + l) * 8;
  f32x4 acc0 = {0.f, 0.f, 0.f, 0.f}, acc1 = {0.f, 0.f, 0.f, 0.f};
#pragma unroll
  for (int ks = 0; ks < 8; ++ks) {
    bf16x8 bv;
#pragma unroll
    for (int j = 0; j < 8; ++j) bv[j] = (short)f2bf(fmaxf(e[ks * 8 + j], 0.f));
    bf16x8 a0 = *reinterpret_cast<const bf16x8*>(Ab + (size_t)(0 * 8 + ks) * 64 * 8);
    bf16x8 a1 = *reinterpret_cast<const bf16x8*>(Ab + (size_t)(1 * 8 + ks) * 64 * 8);
    acc0 = __builtin_amdgcn_mfma_f32_16x16x32_bf16(a0, bv, acc0, 0, 0, 0);
    acc1 = __builtin_amdgcn_mfma_f32_16x16x32_bf16(a1, bv, acc1, 0, 0, 0);
  }

  // epilogue: C/D layout col(px)=lane&15, row(o)=(lane>>4)*4+reg (+16 for tile1)
  const float4 b1a = reinterpret_cast<const float4*>(c1b)[l >> 4];
  const float4 b1b = reinterpret_cast<const float4*>(c1b)[(l >> 4) + 4];
  const float4 w2a = reinterpret_cast<const float4*>(c2w)[l >> 4];
  const float4 w2b = reinterpret_cast<const float4*>(c2w)[(l >> 4) + 4];
  float z = 0.f;
  z = fmaf(w2a.x, fmaxf(acc0[0] + b1a.x, 0.f), z);
  z = fmaf(w2a.y, fmaxf(acc0[1] + b1a.y, 0.f), z);
  z = fmaf(w2a.z, fmaxf(acc0[2] + b1a.z, 0.f), z);
  z = fmaf(w2a.w, fmaxf(acc0[3] + b1a.w, 0.f), z);
  z = fmaf(w2b.x, fmaxf(acc1[0] + b1b.x, 0.f), z);
  z = fmaf(w2b.y, fmaxf(acc1[1] + b1b.y, 0.f), z);
  z = fmaf(w2b.z, fmaxf(acc1[2] + b1b.z, 0.f), z);
  z = fmaf(w2b.w, fmaxf(acc1[3] + b1b.w, 0.f), z);
  // lanes {l&15, +16, +32, +48} sum -> every lane ends with z for ITS pixel
  z += __shfl_xor(z, 16);
  z += __shfl_xor(z, 32);
  const float s = 1.f / (1.f + __expf(-(z + c2b[0])));

  if (l < 16) out[(size_t)b * HW + px0 + l] = s;

  // ---- feature store straight from registers (cached: L2 merges 64B chunks) ----
  float* fp = out + (size_t)NB * HW + (size_t)b * Dq * HW + px0 + (l & 15);
#pragma unroll
  for (int j = 0; j < 64; ++j) {
    const int ch = (j >> 3) * 32 + krow + (j & 7);
    fp[(size_t)ch * HW] = s * e[j];
  }
}

extern "C" void kernel_launch(void* const* d_in, const int* in_sizes, int n_in,
                              void* d_out, int out_size, void* d_ws, size_t ws_size,
                              hipStream_t stream) {
  const float* ent    = (const float*)d_in[0];
  const float* oh     = (const float*)d_in[1];
  const float* W_emb  = (const float*)d_in[2];
  const float* b_emb  = (const float*)d_in[3];
  const float* conv_w = (const float*)d_in[4];
  const float* conv_b = (const float*)d_in[5];
  const float* c1w    = (const float*)d_in[6];
  const float* c1b    = (const float*)d_in[7];
  const float* c2w    = (const float*)d_in[8];
  const float* c2b    = (const float*)d_in[9];
  const int*   h1     = (const int*)d_in[10];
  const int*   h2     = (const int*)d_in[11];
  const float* s1     = (const float*)d_in[12];
  const float* s2     = (const float*)d_in[13];

  float* ws  = (float*)d_ws;
  float* sk1 = ws;                                        // 32*256 f32
  unsigned short* Abuf = (unsigned short*)(ws + NB * Dq); // 32*16*64*8 bf16

  hipLaunchKernelGGL(k_sk1, dim3(NB), dim3(256), 0, stream,
                     oh, W_emb, b_emb, conv_w, conv_b, h1, s1, sk1);
  hipLaunchKernelGGL(k_G, dim3(NB * 32), dim3(256), 0, stream,
                     sk1, c1w, h2, s2, Abuf);
  hipLaunchKernelGGL(k_fused, dim3(HW / 64, NB), dim3(256), 0, stream,
                     ent, Abuf, c1b, c2w, c2b, (float*)d_out);
}

// Round 11
// 80.625 us; speedup vs baseline: 1.0821x; 1.0821x over previous
//
#include <hip/hip_runtime.h>

#define Dq   256
#define ATTR 400
#define HW   3136
#define NB   32

typedef __attribute__((ext_vector_type(8))) short bf16x8;
typedef __attribute__((ext_vector_type(4))) float f32x4;

__device__ __forceinline__ unsigned short f2bf(float f) {
  unsigned int x = __float_as_uint(f);
  return (unsigned short)((x + 0x7FFFu + ((x >> 16) & 1u)) >> 16);
}

// ---------------- Kernel A: per-batch count-sketch vector sk1[b][256] ----------------
__global__ __launch_bounds__(256) void k_sk1(
    const float* __restrict__ oh, const float* __restrict__ W_emb,
    const float* __restrict__ b_emb, const float* __restrict__ conv_w,
    const float* __restrict__ conv_b, const int* __restrict__ h1,
    const float* __restrict__ s1, float* __restrict__ sk1_out) {
  __shared__ float ohs[ATTR];
  __shared__ float ts[Dq];
  __shared__ float sk[Dq];
  const int b = blockIdx.x, tid = threadIdx.x;
  for (int j = tid; j < ATTR; j += 256) ohs[j] = oh[b * ATTR + j];
  sk[tid] = 0.f;
  __syncthreads();
  float acc = b_emb[tid];
  const float* wr = W_emb + tid * ATTR;
  for (int j = 0; j < ATTR; ++j) acc = fmaf(ohs[j], wr[j], acc);
  ts[tid] = acc;
  __syncthreads();
  float a = conv_b[tid];
  const float* cr = conv_w + tid * Dq;
  for (int k = 0; k < Dq; ++k) a = fmaf(ts[k], cr[k], a);
  atomicAdd(&sk[h1[tid]], a * s1[tid]);
  __syncthreads();
  sk1_out[b * Dq + tid] = sk[tid];
}

// ---------------- Kernel B: circular conv + scatter straight into MFMA A-fragment layout ----------------
// Block (b,o). thread tid = c. Writes Abuf[b][frag][lane][j] (bf16) where
// A[m=o][k=c] = G[b][c][o] = s2[c] * T[o,h2[c]]:
//   frag = (o>>4)*8 + (c>>5), lane = (o&15) | (((c>>3)&3)<<4), j = c&7.
__global__ __launch_bounds__(256) void k_G(
    const float* __restrict__ sk1, const float* __restrict__ conv1_w,
    const int* __restrict__ h2, const float* __restrict__ s2,
    unsigned short* __restrict__ Abuf) {
  __shared__ float sks[Dq];
  __shared__ float w1[Dq];
  __shared__ float Tl[Dq];
  const int b = blockIdx.x >> 5, o = blockIdx.x & 31, c = threadIdx.x;
  sks[c] = sk1[b * Dq + c];
  w1[c]  = conv1_w[o * Dq + c];
  __syncthreads();
  float t = 0.f;
  for (int d = 0; d < Dq; ++d) t = fmaf(w1[d], sks[(d - c) & 255], t);
  Tl[c] = t;
  __syncthreads();
  const float g = s2[c] * Tl[h2[c]];
  const int frag = (o >> 4) * 8 + (c >> 5);
  const int lane = (o & 15) | (((c >> 3) & 3) << 4);
  Abuf[(((size_t)b * 16 + frag) * 64 + lane) * 8 + (c & 7)] = f2bf(g);
}

// ---------------- Fused kernel v3: float4 loads, 4 MFMAs/step, 64 px per wave ----------------
// Block = 1 wave = 64 px x 256 ch. Lane l: n = l&15 (pixel group 4n..4n+3),
// kg = l>>4. Phase 1: per ks, 8x float4 loads (16B/lane, 4x in-flight bytes
// vs scalar); component q of each float4 feeds MFMA q (pixel 4n+q).
// Phase 2: float4 re-read (L2/L3-hot) * sigmoid, float4 cached stores.
__global__ __launch_bounds__(64) void k_fused(
    const float* __restrict__ ent,            // [B,256,HW]
    const unsigned short* __restrict__ Abuf,  // [B,16,64,8]
    const float* __restrict__ c1b, const float* __restrict__ c2w,
    const float* __restrict__ c2b,
    float* __restrict__ out)                  // map [B,HW] then feat [B,256,HW]
{
  const int b = blockIdx.y, l = threadIdx.x;
  const int n = l & 15, kg = l >> 4;
  const int px_base = blockIdx.x * 64;          // 49*64 = 3136 exact

  const float* ep = ent + (size_t)b * Dq * HW + px_base + 4 * n;
  const unsigned short* Ab = Abuf + ((size_t)b * 16 * 64 + l) * 8;

  f32x4 acc[4][2];
#pragma unroll
  for (int q = 0; q < 4; ++q) { acc[q][0] = f32x4{0,0,0,0}; acc[q][1] = f32x4{0,0,0,0}; }

#pragma unroll
  for (int ks = 0; ks < 8; ++ks) {
    // 8 float4 loads: channels ks*32 + kg*8 + j, pixels 4n..4n+3
    f32x4 f[8];
#pragma unroll
    for (int j = 0; j < 8; ++j)
      f[j] = *reinterpret_cast<const f32x4*>(ep + (size_t)(ks * 32 + kg * 8 + j) * HW);

    bf16x8 a0 = *reinterpret_cast<const bf16x8*>(Ab + (size_t)(0 * 8 + ks) * 64 * 8);
    bf16x8 a1 = *reinterpret_cast<const bf16x8*>(Ab + (size_t)(1 * 8 + ks) * 64 * 8);

#pragma unroll
    for (int q = 0; q < 4; ++q) {
      bf16x8 bv;
#pragma unroll
      for (int j = 0; j < 8; ++j) bv[j] = (short)f2bf(fmaxf(f[j][q], 0.f));
      acc[q][0] = __builtin_amdgcn_mfma_f32_16x16x32_bf16(a0, bv, acc[q][0], 0, 0, 0);
      acc[q][1] = __builtin_amdgcn_mfma_f32_16x16x32_bf16(a1, bv, acc[q][1], 0, 0, 0);
    }
  }

  // epilogue: C/D col(px-group)=l&15, row(o)=kg*4+reg (+16 for tile 1)
  const float4 b1a = reinterpret_cast<const float4*>(c1b)[kg];
  const float4 b1b = reinterpret_cast<const float4*>(c1b)[kg + 4];
  const float4 w2a = reinterpret_cast<const float4*>(c2w)[kg];
  const float4 w2b = reinterpret_cast<const float4*>(c2w)[kg + 4];
  const float c2b0 = c2b[0];

  f32x4 s4;
#pragma unroll
  for (int q = 0; q < 4; ++q) {
    float z = 0.f;
    z = fmaf(w2a.x, fmaxf(acc[q][0][0] + b1a.x, 0.f), z);
    z = fmaf(w2a.y, fmaxf(acc[q][0][1] + b1a.y, 0.f), z);
    z = fmaf(w2a.z, fmaxf(acc[q][0][2] + b1a.z, 0.f), z);
    z = fmaf(w2a.w, fmaxf(acc[q][0][3] + b1a.w, 0.f), z);
    z = fmaf(w2b.x, fmaxf(acc[q][1][0] + b1b.x, 0.f), z);
    z = fmaf(w2b.y, fmaxf(acc[q][1][1] + b1b.y, 0.f), z);
    z = fmaf(w2b.z, fmaxf(acc[q][1][2] + b1b.z, 0.f), z);
    z = fmaf(w2b.w, fmaxf(acc[q][1][3] + b1b.w, 0.f), z);
    z += __shfl_xor(z, 16);
    z += __shfl_xor(z, 32);
    s4[q] = 1.f / (1.f + __expf(-(z + c2b0)));
  }

  // attr_map: lanes 0..15 store float4 for pixels px_base+4l..+3
  if (l < 16)
    *reinterpret_cast<f32x4*>(out + (size_t)b * HW + px_base + 4 * l) = s4;

  // ---- phase 2: feature store; entity re-read is L2/L3-hot ----
  const size_t fbase = (size_t)NB * HW + (size_t)b * Dq * HW + px_base + 4 * n;
  float* fp = out + fbase;
#pragma unroll 8
  for (int cc = 0; cc < 64; ++cc) {
    const size_t off = (size_t)(kg * 64 + cc) * HW;
    f32x4 e = *reinterpret_cast<const f32x4*>(ep + off);
    *reinterpret_cast<f32x4*>(fp + off) = e * s4;
  }
}

extern "C" void kernel_launch(void* const* d_in, const int* in_sizes, int n_in,
                              void* d_out, int out_size, void* d_ws, size_t ws_size,
                              hipStream_t stream) {
  const float* ent    = (const float*)d_in[0];
  const float* oh     = (const float*)d_in[1];
  const float* W_emb  = (const float*)d_in[2];
  const float* b_emb  = (const float*)d_in[3];
  const float* conv_w = (const float*)d_in[4];
  const float* conv_b = (const float*)d_in[5];
  const float* c1w    = (const float*)d_in[6];
  const float* c1b    = (const float*)d_in[7];
  const float* c2w    = (const float*)d_in[8];
  const float* c2b    = (const float*)d_in[9];
  const int*   h1     = (const int*)d_in[10];
  const int*   h2     = (const int*)d_in[11];
  const float* s1     = (const float*)d_in[12];
  const float* s2     = (const float*)d_in[13];

  float* ws  = (float*)d_ws;
  float* sk1 = ws;                                        // 32*256 f32
  unsigned short* Abuf = (unsigned short*)(ws + NB * Dq); // 32*16*64*8 bf16

  hipLaunchKernelGGL(k_sk1, dim3(NB), dim3(256), 0, stream,
                     oh, W_emb, b_emb, conv_w, conv_b, h1, s1, sk1);
  hipLaunchKernelGGL(k_G, dim3(NB * 32), dim3(256), 0, stream,
                     sk1, c1w, h2, s2, Abuf);
  hipLaunchKernelGGL(k_fused, dim3(49, NB), dim3(64), 0, stream,
                     ent, Abuf, c1b, c2w, c2b, (float*)d_out);
}